// Round 12
// baseline (274.194 us; speedup 1.0000x reference)
//
#include <hip/hip_runtime.h>
#include <math.h>

typedef __bf16 bf16x8 __attribute__((ext_vector_type(8)));
typedef __bf16 bf16x4 __attribute__((ext_vector_type(4)));
typedef float  floatx4 __attribute__((ext_vector_type(4)));
typedef float  floatx2 __attribute__((ext_vector_type(2)));

#define AS1(p) ((__attribute__((address_space(1))) void*)(p))
#define AS3(p) ((__attribute__((address_space(3))) void*)(p))

#define MASKV (-1.0e30f)
#define SOFTMAX_SCALE_LOG2 0.1803368801111244f   // 0.125 * log2(e)
#define ROPE_LOG2F 0.4152410118609203f           // log2(10000)/32

// ---------------------------------------------------------------------------
// One-shot fp32 -> bf16 conversion of x/qkv/wo + rope cos/sin table build.
// ---------------------------------------------------------------------------
__global__ __launch_bounds__(256)
void cvt3_kernel(const float* __restrict__ x, const float* __restrict__ qkv,
                 const float* __restrict__ wo, __bf16* __restrict__ xb,
                 __bf16* __restrict__ qkvb, __bf16* __restrict__ wob,
                 float* __restrict__ rt)
{
    const int bi = blockIdx.x;
    if (bi >= 12288) {
        const int e0 = (bi - 12288) * 1024 + threadIdx.x * 4;
#pragma unroll
        for (int j = 0; j < 4; ++j) {
            const int e = e0 + j;
            const int s = e >> 5, d = e & 31;
            const float f = exp2f(-(float)d * ROPE_LOG2F);
            float sn, cs;
            sincosf((float)s * f, &sn, &cs);
            floatx2 t; t[0] = cs; t[1] = sn;
            *(floatx2*)(rt + e * 2) = t;
        }
        return;
    }
    const float* src;
    __bf16* dst;
    int base;
    if (bi < 8192)       { src = x;   dst = xb;   base = bi * 1024; }
    else if (bi < 11264) { src = qkv; dst = qkvb; base = (bi - 8192) * 1024; }
    else                 { src = wo;  dst = wob;  base = (bi - 11264) * 1024; }

    const int i = base + threadIdx.x * 4;
    const floatx4 v = *(const floatx4*)(src + i);
    bf16x4 o;
    o[0] = (__bf16)v[0]; o[1] = (__bf16)v[1];
    o[2] = (__bf16)v[2]; o[3] = (__bf16)v[3];
    *(bf16x4*)(dst + i) = o;
}

// ---------------------------------------------------------------------------
// GEMM1 + fused RoPE (table) + head-major scatter (unchanged from R11).
// ---------------------------------------------------------------------------
__global__ __launch_bounds__(256)
void gemm_rope_kernel(const __bf16* __restrict__ A, const __bf16* __restrict__ BT,
                      __bf16* __restrict__ Qr, __bf16* __restrict__ Kr,
                      __bf16* __restrict__ Vt, const float* __restrict__ rt)
{
    const int K = 1024;
    __shared__ __align__(16) __bf16 As[128 * 32];
    __shared__ __align__(16) __bf16 Bs[128 * 32];

    const int tid  = threadIdx.x;
    const int wave = tid >> 6;
    const int lane = tid & 63;
    const int quad = lane >> 4;
    const int l16  = lane & 15;

    const long m0 = (long)blockIdx.y * 128;
    const long n0 = (long)blockIdx.x * 128;
    const int  wm = (wave >> 1) * 64;
    const int  wn = (wave & 1) * 64;

    floatx4 acc[4][4] = {};

    for (int k0 = 0; k0 < K; k0 += 32) {
#pragma unroll
        for (int t = 0; t < 2; ++t) {
            const int c   = (t * 4 + wave) * 64 + lane;
            const int row = c >> 2;
            const int kc  = (c & 3) * 8;
            const __bf16* ga = A  + (m0 + row) * (long)K + k0 + kc;
            const __bf16* gb = BT + (n0 + row) * (long)K + k0 + kc;
            __builtin_amdgcn_global_load_lds(AS1(ga), AS3(As + (t * 4 + wave) * 512), 16, 0, 0);
            __builtin_amdgcn_global_load_lds(AS1(gb), AS3(Bs + (t * 4 + wave) * 512), 16, 0, 0);
        }
        asm volatile("s_waitcnt vmcnt(0)" ::: "memory");
        __syncthreads();

        bf16x8 af[4], bfq[4];
#pragma unroll
        for (int mt = 0; mt < 4; ++mt)
            af[mt] = *(const bf16x8*)(As + (wm + mt * 16 + l16) * 32 + quad * 8);
#pragma unroll
        for (int nt = 0; nt < 4; ++nt)
            bfq[nt] = *(const bf16x8*)(Bs + (wn + nt * 16 + l16) * 32 + quad * 8);

#pragma unroll
        for (int mt = 0; mt < 4; ++mt)
#pragma unroll
            for (int nt = 0; nt < 4; ++nt)
                acc[mt][nt] = __builtin_amdgcn_mfma_f32_16x16x32_bf16(
                    af[mt], bfq[nt], acc[mt][nt], 0, 0, 0);
        __syncthreads();
    }

    const int gn0    = (int)n0 + wn;
    const int region = gn0 >> 10;           // 0=Q, 1=K, 2=V
    const int h      = (gn0 >> 6) & 15;

    if (region == 2) {
#pragma unroll
        for (int mt = 0; mt < 4; ++mt) {
            const long gm = m0 + wm + mt * 16 + quad * 4;
            const int  b  = (int)(gm >> 11), s = (int)(gm & 2047);
#pragma unroll
            for (int nt = 0; nt < 4; ++nt) {
                const int d = nt * 16 + l16;
                bf16x4 w;
#pragma unroll
                for (int r = 0; r < 4; ++r) w[r] = (__bf16)acc[mt][nt][r];
                *(bf16x4*)(Vt + ((size_t)(b * 16 + h) * 64 + d) * 2048 + s) = w;
            }
        }
    } else {
        __bf16* dst = region ? Kr : Qr;
#pragma unroll
        for (int nt = 0; nt < 2; ++nt) {
            const int d1 = nt * 16 + l16;
#pragma unroll
            for (int mt = 0; mt < 4; ++mt) {
                const long gm0 = m0 + wm + mt * 16 + quad * 4;
                const int  b   = (int)(gm0 >> 11), s0 = (int)(gm0 & 2047);
#pragma unroll
                for (int r = 0; r < 4; ++r) {
                    const floatx2 t = *(const floatx2*)(rt + ((s0 + r) * 32 + d1) * 2);
                    const float a1 = acc[mt][nt][r];
                    const float a2 = acc[mt][nt + 2][r];
                    __bf16* row = dst + ((size_t)((b * 16 + h) * 2048 + s0 + r)) * 64;
                    row[d1]      = (__bf16)(a1 * t[0] - a2 * t[1]);
                    row[d1 + 32] = (__bf16)(a2 * t[0] + a1 * t[1]);
                }
            }
        }
    }
}

// ---------------------------------------------------------------------------
// GEMM2: C[M][N] = A[M][K] * BT[N][K]^T (bf16 in, fp32 out).
// ---------------------------------------------------------------------------
__global__ __launch_bounds__(256)
void gemm_bt_kernel(const __bf16* __restrict__ A, const __bf16* __restrict__ BT,
                    float* __restrict__ C, int M, int N, int K)
{
    __shared__ __align__(16) __bf16 As[128 * 32];
    __shared__ __align__(16) __bf16 Bs[128 * 32];

    const int tid  = threadIdx.x;
    const int wave = tid >> 6;
    const int lane = tid & 63;
    const int quad = lane >> 4;
    const int l16  = lane & 15;

    const long m0 = (long)blockIdx.y * 128;
    const long n0 = (long)blockIdx.x * 128;
    const int  wm = (wave >> 1) * 64;
    const int  wn = (wave & 1) * 64;

    floatx4 acc[4][4] = {};

    for (int k0 = 0; k0 < K; k0 += 32) {
#pragma unroll
        for (int t = 0; t < 2; ++t) {
            const int c   = (t * 4 + wave) * 64 + lane;
            const int row = c >> 2;
            const int kc  = (c & 3) * 8;
            const __bf16* ga = A  + (m0 + row) * (long)K + k0 + kc;
            const __bf16* gb = BT + (n0 + row) * (long)K + k0 + kc;
            __builtin_amdgcn_global_load_lds(AS1(ga), AS3(As + (t * 4 + wave) * 512), 16, 0, 0);
            __builtin_amdgcn_global_load_lds(AS1(gb), AS3(Bs + (t * 4 + wave) * 512), 16, 0, 0);
        }
        asm volatile("s_waitcnt vmcnt(0)" ::: "memory");
        __syncthreads();

        bf16x8 af[4], bfq[4];
#pragma unroll
        for (int mt = 0; mt < 4; ++mt)
            af[mt] = *(const bf16x8*)(As + (wm + mt * 16 + l16) * 32 + quad * 8);
#pragma unroll
        for (int nt = 0; nt < 4; ++nt)
            bfq[nt] = *(const bf16x8*)(Bs + (wn + nt * 16 + l16) * 32 + quad * 8);

#pragma unroll
        for (int mt = 0; mt < 4; ++mt)
#pragma unroll
            for (int nt = 0; nt < 4; ++nt)
                acc[mt][nt] = __builtin_amdgcn_mfma_f32_16x16x32_bf16(
                    af[mt], bfq[nt], acc[mt][nt], 0, 0, 0);
        __syncthreads();
    }

#pragma unroll
    for (int mt = 0; mt < 4; ++mt)
#pragma unroll
        for (int nt = 0; nt < 4; ++nt) {
            const long row = m0 + wm + mt * 16 + quad * 4;
            const long col = n0 + wn + nt * 16 + l16;
#pragma unroll
            for (int r = 0; r < 4; ++r)
                C[(row + r) * (long)N + col] = acc[mt][nt][r];
        }
}

// ---------------------------------------------------------------------------
// Causal flash attention v7 — DOUBLE-BUFFERED cooperative staging.
// grid = (64 bh, 8), block = 256. Each block runs 4 uniform q-tiles
// {ty, 31-ty, 8+ty, 23-ty} (66 iters total). Per iter: issue next tile's
// 16 global_load_lds into buffer cur^1 BEFORE computing on cur; single
// vmcnt(0)+barrier after compute (loads land under compute -> ~0 stall).
// One barrier/iter (v6 had drain+2 barriers on the critical path).
// LDS: KV 2x16KB + plds 9KB = 42KB -> 3 blocks/CU; 512 blocks all resident.
// ---------------------------------------------------------------------------
#define STAGE(kt, bf)                                                                              \
    do {                                                                                           \
        __builtin_amdgcn_global_load_lds(AS1(Kb + (size_t)((kt) + row0) * 64 + jg0 * 8),           \
                                         AS3(KV[bf][0] + wave * 512), 16, 0, 0);                   \
        __builtin_amdgcn_global_load_lds(AS1(Vb + (size_t)row0 * 2048 + (kt) + jg0 * 8),           \
                                         AS3(KV[bf][1] + wave * 512), 16, 0, 0);                   \
        __builtin_amdgcn_global_load_lds(AS1(Kb + (size_t)((kt) + row1) * 64 + jg1 * 8),           \
                                         AS3(KV[bf][0] + (4 + wave) * 512), 16, 0, 0);             \
        __builtin_amdgcn_global_load_lds(AS1(Vb + (size_t)row1 * 2048 + (kt) + jg1 * 8),           \
                                         AS3(KV[bf][1] + (4 + wave) * 512), 16, 0, 0);             \
    } while (0)

__global__ __launch_bounds__(256, 3)
void attn_kernel(const __bf16* __restrict__ Qr, const __bf16* __restrict__ Kr,
                 const __bf16* __restrict__ Vt, __bf16* __restrict__ ctx)
{
    __shared__ __align__(16) __bf16 KV[2][2][64 * 64];  // [buf][K|V], swizzled
    __shared__ __align__(16) __bf16 plds[4][16 * 72];   // wave-private P staging

    const int bh   = blockIdx.x;
    const int b    = bh >> 4, h = bh & 15;
    const int tid  = threadIdx.x;
    const int wave = tid >> 6;
    const int lane = tid & 63;
    const int quad = lane >> 4, l16 = lane & 15;
    const int sw   = l16 & 7;                 // read-side XOR swizzle

    const __bf16* Qb = Qr + (size_t)bh * 2048 * 64;
    const __bf16* Kb = Kr + (size_t)bh * 2048 * 64;
    const __bf16* Vb = Vt + (size_t)bh * 64 * 2048;
    __bf16* Pw = &plds[wave][0];

    const int c0   = tid;
    const int row0 = c0 >> 3, jg0 = (c0 & 7) ^ (row0 & 7);
    const int c1   = 256 + tid;
    const int row1 = c1 >> 3, jg1 = (c1 & 7) ^ (row1 & 7);

    const int ty = (int)blockIdx.y;
    const int tiles[4] = { ty, 31 - ty, 8 + ty, 23 - ty };   // uniform: 66 iters

    for (int pass = 0; pass < 4; ++pass) {
        const int q0b  = tiles[pass] * 64;
        const int q0   = q0b + wave * 16;
        const int qa   = q0 + l16;
        const int kend = q0b + 64;

        bf16x8 bq[2];
#pragma unroll
        for (int t = 0; t < 2; ++t)
            bq[t] = *(const bf16x8*)(Qb + (q0 + l16) * 64 + t * 32 + quad * 8);

        floatx4 o[4] = {};
        float lpart = 0.f;

        // prologue: stage tile 0 into buf 0
        STAGE(0, 0);
        asm volatile("s_waitcnt vmcnt(0)" ::: "memory");
        __syncthreads();

        int cur = 0;
        for (int kt = 0; kt < kend; kt += 64) {
            // fire next tile's staging into the other buffer
            if (kt + 64 < kend)
                STAGE(kt + 64, cur ^ 1);

            const __bf16* Ks = KV[cur][0];
            const __bf16* Vs = KV[cur][1];

            floatx4 s[4] = {};
#pragma unroll
            for (int st = 0; st < 4; ++st) {
                bf16x8 ka0 = *(const bf16x8*)(Ks + (st * 16 + l16) * 64 + ((0 + quad) ^ sw) * 8);
                bf16x8 ka1 = *(const bf16x8*)(Ks + (st * 16 + l16) * 64 + ((4 + quad) ^ sw) * 8);
                s[st] = __builtin_amdgcn_mfma_f32_16x16x32_bf16(ka0, bq[0], s[st], 0, 0, 0);
                s[st] = __builtin_amdgcn_mfma_f32_16x16x32_bf16(ka1, bq[1], s[st], 0, 0, 0);
            }

#pragma unroll
            for (int st = 0; st < 4; ++st) {
                bf16x4 w;
#pragma unroll
                for (int r = 0; r < 4; ++r) {
                    const int key = kt + st * 16 + quad * 4 + r;
                    const float v = (key > qa) ? MASKV : s[st][r] * SOFTMAX_SCALE_LOG2;
                    const float p = __builtin_amdgcn_exp2f(v);
                    lpart += p;
                    w[r] = (__bf16)p;
                }
                *(bf16x4*)(Pw + l16 * 72 + st * 16 + quad * 4) = w;
            }

            asm volatile("s_waitcnt lgkmcnt(0)" ::: "memory");
            bf16x8 ap0 = *(const bf16x8*)(Pw + l16 * 72 + quad * 8);
            bf16x8 ap1 = *(const bf16x8*)(Pw + l16 * 72 + 32 + quad * 8);

#pragma unroll
            for (int nt = 0; nt < 4; ++nt) {
                bf16x8 bv0 = *(const bf16x8*)(Vs + (nt * 16 + l16) * 64 + ((0 + quad) ^ sw) * 8);
                bf16x8 bv1 = *(const bf16x8*)(Vs + (nt * 16 + l16) * 64 + ((4 + quad) ^ sw) * 8);
                o[nt] = __builtin_amdgcn_mfma_f32_16x16x32_bf16(ap0, bv0, o[nt], 0, 0, 0);
                o[nt] = __builtin_amdgcn_mfma_f32_16x16x32_bf16(ap1, bv1, o[nt], 0, 0, 0);
            }

            // next tile's loads have had the whole compute to land
            asm volatile("s_waitcnt vmcnt(0)" ::: "memory");
            __syncthreads();
            cur ^= 1;
        }

        float l = lpart;
        l += __shfl_xor(l, 16, 64);
        l += __shfl_xor(l, 32, 64);
        float lr[4];
#pragma unroll
        for (int r = 0; r < 4; ++r)
            lr[r] = __shfl(l, quad * 4 + r, 64);
#pragma unroll
        for (int nt = 0; nt < 4; ++nt)
#pragma unroll
            for (int r = 0; r < 4; ++r) {
                const int srow = q0 + quad * 4 + r;
                const float inv_l = 1.0f / fmaxf(lr[r], 1e-20f);
                ctx[((size_t)(b * 2048 + srow)) * 1024 + h * 64 + nt * 16 + l16] =
                    (__bf16)(o[nt][r] * inv_l);
            }
    }
}

// ---------------------------------------------------------------------------
// Workspace layout (88.5 MiB):
//   xb   [ 0M..16M)   qkvb [16M..22M)   wob [22M..24M)
//   Qr   [24M..40M)   Kr   [40M..56M)   Vt  [56M..72M)   ctx [72M..88M)
//   rt   [88M..88.5M) rope cos/sin table (2048 x 32 float2)
// ---------------------------------------------------------------------------
extern "C" void kernel_launch(void* const* d_in, const int* in_sizes, int n_in,
                              void* d_out, int out_size, void* d_ws, size_t ws_size,
                              hipStream_t stream)
{
    const float* x   = (const float*)d_in[0];   // [4,2048,1024] fp32
    const float* qkv = (const float*)d_in[1];   // [3072,1024]   fp32 (N x K)
    const float* wo  = (const float*)d_in[2];   // [1024,1024]   fp32 (N x K)
    float* out = (float*)d_out;                 // [8192,1024]   fp32

    char* ws = (char*)d_ws;
    const size_t MB = 1024 * 1024;
    __bf16* xb   = (__bf16*)(ws);
    __bf16* qkvb = (__bf16*)(ws + 16 * MB);
    __bf16* wob  = (__bf16*)(ws + 22 * MB);
    __bf16* Qr   = (__bf16*)(ws + 24 * MB);
    __bf16* Kr   = (__bf16*)(ws + 40 * MB);
    __bf16* Vt   = (__bf16*)(ws + 56 * MB);
    __bf16* ctx  = (__bf16*)(ws + 72 * MB);
    float*  rt   = (float*) (ws + 88 * MB);

    cvt3_kernel<<<12352, 256, 0, stream>>>(x, qkv, wo, xb, qkvb, wob, rt);
    gemm_rope_kernel<<<dim3(24, 64), 256, 0, stream>>>(xb, qkvb, Qr, Kr, Vt, rt);
    attn_kernel<<<dim3(64, 8), 256, 0, stream>>>(Qr, Kr, Vt, ctx);
    gemm_bt_kernel<<<dim3(8, 64), 256, 0, stream>>>(ctx, wob, out, 8192, 1024, 1024);
}